// Round 3
// baseline (210.424 us; speedup 1.0000x reference)
//
#include <hip/hip_runtime.h>
#include <hip/hip_bf16.h>

#define D 1024      // in_features
#define E 64        // num experts
#define TPB 256     // threads per block (4 waves)
#define TOKS 64     // tokens per block (16 per wave)
#define KC 64       // k per staged W chunk (2 MFMA k-steps)
#define BROW 72     // padded bf16 row length (72*2B = 144B = 9*16B -> 16B-aligned rows)

typedef __attribute__((ext_vector_type(8))) short bf16x8;
typedef __attribute__((ext_vector_type(4))) float f32x4;
typedef __attribute__((ext_vector_type(4))) int i32x4;
typedef __attribute__((ext_vector_type(4))) unsigned short u16x4;

__device__ __forceinline__ unsigned short bf16_rne(float f) {
    unsigned u = __builtin_bit_cast(unsigned, f);
    u += 0x7fffu + ((u >> 16) & 1u);
    return (unsigned short)(u >> 16);
}
__device__ __forceinline__ float bf16_as_f(unsigned short h) {
    unsigned u = ((unsigned)h) << 16;
    return __builtin_bit_cast(float, u);
}
__device__ __forceinline__ void split_hi_lo(float v, unsigned short& h, unsigned short& l) {
    h = bf16_rne(v);
    l = bf16_rne(v - bf16_as_f(h));
}

// ---- pre-kernel: split W (fp32) into hi/lo bf16 planes in d_ws (runs every call) ----
__global__ __launch_bounds__(256) void wsplit_kernel(const float* __restrict__ W,
        unsigned short* __restrict__ whi, unsigned short* __restrict__ wlo) {
    int g = blockIdx.x * 256 + threadIdx.x;     // 16384 threads x 4 elems = 64K
    f32x4 w = *(const f32x4*)(W + (size_t)g * 4);
    u16x4 h, l;
#pragma unroll
    for (int j = 0; j < 4; ++j) {
        unsigned short hh, ll;
        split_hi_lo(w[j], hh, ll);
        h[j] = hh; l[j] = ll;
    }
    *(u16x4*)(whi + (size_t)g * 4) = h;
    *(u16x4*)(wlo + (size_t)g * 4) = l;
}

__global__ __launch_bounds__(TPB) void router_kernel(
        const float* __restrict__ x,
        const unsigned short* __restrict__ whi,
        const unsigned short* __restrict__ wlo,
        const float* __restrict__ bias,
        float* __restrict__ out, int T) {
    // LDS: staged W chunk (hi/lo bf16, padded rows) unioned with epilogue logits
    // (identical layout to the round-1 PASSING kernel)
    __shared__ __align__(16) union SM {
        struct { unsigned short hi[E][BROW]; unsigned short lo[E][BROW]; } b;
        float ls[TOKS][E + 1];
    } sm;
    __shared__ float sbias[E];

    const int tid  = threadIdx.x;
    const int lane = tid & 63;
    const int wid  = tid >> 6;     // wave id 0..3 -> 16-token strip
    const int n    = lane & 15;    // MFMA m/n index within tile
    const int q    = lane >> 4;    // MFMA quad -> k offset q*8
    const int t0   = blockIdx.x * TOKS;

    if (tid < E) sbias[tid] = bias[tid];

    f32x4 acc[4];
#pragma unroll
    for (int i = 0; i < 4; ++i) acc[i] = (f32x4){0.f, 0.f, 0.f, 0.f};

    // A source: this lane reads 8 consecutive fp32 per k-step, MFMA lane order
    const float* arow = x + (size_t)(t0 + wid * 16 + n) * D + q * 8;

    // W staging geometry: 4 slots/thread; slot r: plane p=r>>1 (0=hi,1=lo),
    // idx=(r&1)*256+tid in [0,512): expert e=idx>>3, 16B-block blk=idx&7.
    // Per chunk/plane: 64 experts x 64 k x 2B = 8 KB = 512 x 16B.  [bf16 copy, no split]
    i32x4 wreg[4];
    auto load_w = [&](int kc) {
#pragma unroll
        for (int r = 0; r < 4; ++r) {
            int idx = ((r & 1) << 8) + tid;
            int e = idx >> 3, blk = idx & 7;
            const unsigned short* src = (r >> 1) ? wlo : whi;
            wreg[r] = *(const i32x4*)(src + (size_t)e * D + kc + blk * 8);
        }
    };
    auto store_w = [&]() {
#pragma unroll
        for (int r = 0; r < 4; ++r) {
            int idx = ((r & 1) << 8) + tid;
            int e = idx >> 3, blk = idx & 7;
            unsigned short* dst = (r >> 1) ? &sm.b.lo[e][blk * 8] : &sm.b.hi[e][blk * 8];
            *(i32x4*)dst = wreg[r];   // 16B aligned: e*144 + blk*16
        }
    };

    // ---- prologue: fetch chunk 0 (W regs + A regs) ----
    load_w(0);
    f32x4 areg[4];
#pragma unroll
    for (int s = 0; s < 2; ++s) {
        areg[2 * s]     = *(const f32x4*)(arow + s * 32);
        areg[2 * s + 1] = *(const f32x4*)(arow + s * 32 + 4);
    }

    for (int kc = 0; kc < D; kc += KC) {
        // ---- write staged W chunk into LDS (pure bf16 copy) ----
        store_w();
        __syncthreads();

        // ---- prefetch next chunk (branchless wrap; last iter reloads chunk 0) ----
        int kn = (kc + KC) & (D - 1);
        load_w(kn);
        f32x4 anext[4];
#pragma unroll
        for (int s = 0; s < 2; ++s) {
            anext[2 * s]     = *(const f32x4*)(arow + kn + s * 32);
            anext[2 * s + 1] = *(const f32x4*)(arow + kn + s * 32 + 4);
        }

        // ---- compute: 2 MFMA k-steps per chunk (round-1 verified path) ----
#pragma unroll
        for (int s = 0; s < 2; ++s) {
            unsigned short ah[8], al[8];
#pragma unroll
            for (int j = 0; j < 4; ++j) {
                split_hi_lo(areg[2 * s][j],     ah[j],     al[j]);
                split_hi_lo(areg[2 * s + 1][j], ah[4 + j], al[4 + j]);
            }
            bf16x8 ahv, alv;
#pragma unroll
            for (int j = 0; j < 8; ++j) { ahv[j] = (short)ah[j]; alv[j] = (short)al[j]; }
#pragma unroll
            for (int nt = 0; nt < 4; ++nt) {
                const bf16x8 bh = *(const bf16x8*)&sm.b.hi[nt * 16 + n][s * 32 + q * 8];
                const bf16x8 bl = *(const bf16x8*)&sm.b.lo[nt * 16 + n][s * 32 + q * 8];
                acc[nt] = __builtin_amdgcn_mfma_f32_16x16x32_bf16(ahv, bh, acc[nt], 0, 0, 0);
                acc[nt] = __builtin_amdgcn_mfma_f32_16x16x32_bf16(alv, bh, acc[nt], 0, 0, 0);
                acc[nt] = __builtin_amdgcn_mfma_f32_16x16x32_bf16(ahv, bl, acc[nt], 0, 0, 0);
            }
        }
#pragma unroll
        for (int i = 0; i < 4; ++i) areg[i] = anext[i];
        __syncthreads();
    }

    // ---- epilogue: logits (+bias) to LDS, then per-token softmax + top-2 ----
#pragma unroll
    for (int nt = 0; nt < 4; ++nt) {
        int col = nt * 16 + n;
        float bv = sbias[col];
#pragma unroll
        for (int r = 0; r < 4; ++r) {
            // C/D layout: col = lane&15, row = (lane>>4)*4 + reg
            sm.ls[wid * 16 + q * 4 + r][col] = acc[nt][r] + bv;
        }
    }
    __syncthreads();

    if (tid < TOKS) {
        float m1 = -3.4e38f, m2 = -3.4e38f;
        int i1 = 0, i2 = 0;
        for (int e = 0; e < E; ++e) {
            float v = sm.ls[tid][e];
            if (v > m1) { m2 = m1; i2 = i1; m1 = v; i1 = e; }
            else if (v > m2) { m2 = v; i2 = e; }
        }
        float Z = 0.f;
        for (int e = 0; e < E; ++e) Z += __expf(sm.ls[tid][e] - m1);
        float inv = 1.f / Z;
        int gt = t0 + tid;
        out[(size_t)gt * 2]     = inv;                 // exp(m1-m1)/Z
        out[(size_t)gt * 2 + 1] = __expf(m2 - m1) * inv;
        float* oi = out + (size_t)T * 2;
        oi[(size_t)gt * 2]     = (float)i1;            // indices stored as float values
        oi[(size_t)gt * 2 + 1] = (float)i2;
    }
}

extern "C" void kernel_launch(void* const* d_in, const int* in_sizes, int n_in,
                              void* d_out, int out_size, void* d_ws, size_t ws_size,
                              hipStream_t stream) {
    const float* x = (const float*)d_in[0];
    const float* W = (const float*)d_in[1];
    const float* b = (const float*)d_in[2];
    float* out = (float*)d_out;
    unsigned short* whi = (unsigned short*)d_ws;
    unsigned short* wlo = whi + (size_t)E * D;
    int T = in_sizes[0] / D;                  // 32768 tokens
    hipLaunchKernelGGL(wsplit_kernel, dim3((E * D) / 1024), dim3(256), 0, stream,
                       W, whi, wlo);
    hipLaunchKernelGGL(router_kernel, dim3(T / TOKS), dim3(TPB), 0, stream,
                       x, whi, wlo, b, out, T);
}